// Round 13
// baseline (2068.362 us; speedup 1.0000x reference)
//
#include <hip/hip_runtime.h>

#define NNODES 50000
#define NEDGES 800000

typedef __bf16 bf16x8 __attribute__((ext_vector_type(8)));
typedef short short8 __attribute__((ext_vector_type(8)));
typedef short short4v __attribute__((ext_vector_type(4)));
typedef float f32x4 __attribute__((ext_vector_type(4)));

// ws layout (byte offsets):
#define OFF_FE_W0T 0        // short idx
#define OFF_FE_W1T 81920
#define OFF_FE_W2T 147456
#define OFF_FN_W0T 180224
#define OFF_FN_W1T 245760
#define OFF_FN_W2T 311296   // ends at short 344064 = byte 688128
#define OFF_CNT_B    688128              // int[50000]
#define OFF_BASE_B   888128              // int[50001]
#define OFF_CURSOR_B 1088384             // int[50000]
#define OFF_EIDX_B   1288448             // int[800000]
#define OFF_BSUM_B   4488448             // int[64]
#define OFF_NBF_B    4488704             // short[50000*128] bf16 node table (12.8 MB)
#define OFF_ECOPY_B  17288704            // short[800000*128] bf16 e_out copy (204.8 MB)
#define ECOPY_NEED   (17288704ull + 204800000ull)

__device__ __forceinline__ short f2bf(float f) {
  union { float f; unsigned u; } v; v.f = f;
  unsigned r = v.u + 0x7FFFu + ((v.u >> 16) & 1u);   // RNE
  return (short)(r >> 16);
}
__device__ __forceinline__ float bf2f(short s) {
  union { unsigned u; float f; } v; v.u = ((unsigned)(unsigned short)s) << 16;
  return v.f;
}

typedef const unsigned __attribute__((address_space(1)))* gas_t;
typedef unsigned __attribute__((address_space(3)))* las_t;
__device__ __forceinline__ void gload16(const short* g, short* l) {
  __builtin_amdgcn_global_load_lds((gas_t)(const void*)g, (las_t)(void*)l, 16, 0, 0);
}

#define VMW4 asm volatile("s_waitcnt vmcnt(4)" ::: "memory")
#define VMW0 asm volatile("s_waitcnt vmcnt(0)" ::: "memory")
#define LKW0 asm volatile("s_waitcnt lgkmcnt(0)" ::: "memory")
#define BARX __builtin_amdgcn_s_barrier()
#define SBAR0 __builtin_amdgcn_sched_barrier(0)

__device__ __forceinline__ f32x4 mfma16(bf16x8 a, bf16x8 b, f32x4 c) {
  return __builtin_amdgcn_mfma_f32_16x16x32_bf16(a, b, c, 0, 0, 0);
}

// ---- weight slices through LDS (4-wave / 256-thread block: 4 chunks/thread) ----
// 256-row, 1-K-step slice (16KB): [256 rows][64B]; chunk sl of row r holds
// W[r][kbase + ((sl^((r>>1)&3))*8) .. +8]. Linear gload dest; swizzled read.
template <int WTK>
__device__ __forceinline__ void stage256(const short* __restrict__ Wt, int kbase,
                                         short* slot, int wid, int lane) {
#pragma unroll
  for (int r = 0; r < 4; ++r) {
    int f = (r * 4 + wid) * 64 + lane;    // 1024 chunks of 16B
    int row = f >> 2;
    int sl = f & 3;
    int sig = (row >> 1) & 3;
    const short* src = Wt + row * WTK + kbase + ((sl ^ sig) << 3);
    short* dst = slot + (r * 4 + wid) * 512;   // wave-uniform; HW adds lane*16
    gload16(src, dst);
  }
}

// 128-row, 2-K-step slice (16KB): [128 rows][128B]; chunk sl of row r holds
// W[r][kbase + ((sl^(r&7))*8) .. +8].
__device__ __forceinline__ void stage128(const short* __restrict__ Wt, int kbase,
                                         short* slot, int wid, int lane) {
#pragma unroll
  for (int r = 0; r < 4; ++r) {
    int f = (r * 4 + wid) * 64 + lane;
    int row = f >> 3;
    int sl = f & 7;
    const short* src = Wt + row * 256 + kbase + ((sl ^ (row & 7)) << 3);
    short* dst = slot + (r * 4 + wid) * 512;
    gload16(src, dst);
  }
}

// One K-step over the 32-row tile; wave wc covers cols [wc*64, +64) (NREP=4).
template <int NREP, int LDB>
__device__ __forceinline__ void comp_step(const short* xl, const short* slot, int kk,
                                          int wc, int lane, f32x4 acc[2][NREP]) {
  const int m0 = lane & 15;
  const int g = lane >> 4;
  bf16x8 a[2], b[NREP];
#pragma unroll
  for (int m = 0; m < 2; ++m) {
    int row = m * 16 + m0;
    int byte = row * LDB + kk * 64 + g * 16;
    byte ^= (row & 7) << 4;
    a[m] = *(const bf16x8*)((const char*)xl + byte);
  }
#pragma unroll
  for (int n = 0; n < NREP; ++n) {
    int col = wc * (NREP * 16) + n * 16 + m0;
    int byte = col * 64 + ((g ^ ((col >> 1) & 3)) << 4);
    b[n] = *(const bf16x8*)((const char*)slot + byte);
  }
#pragma unroll
  for (int n = 0; n < NREP; ++n)
#pragma unroll
    for (int m = 0; m < 2; ++m)
      acc[m][n] = mfma16(a[m], b[n], acc[m][n]);
}

// Two K-steps against a 128-row slice (final layer, NREP=2).
template <int LDB>
__device__ __forceinline__ void comp_pairf(const short* xl, const short* slot, int kk0,
                                           int wc, int lane, f32x4 acc[2][2]) {
  const int m0 = lane & 15;
  const int g = lane >> 4;
#pragma unroll
  for (int p = 0; p < 2; ++p) {
    const int kk = kk0 + p;
    bf16x8 a[2], b[2];
#pragma unroll
    for (int m = 0; m < 2; ++m) {
      int row = m * 16 + m0;
      int byte = row * LDB + kk * 64 + g * 16;
      byte ^= (row & 7) << 4;
      a[m] = *(const bf16x8*)((const char*)xl + byte);
    }
#pragma unroll
    for (int n = 0; n < 2; ++n) {
      int col = wc * 32 + n * 16 + m0;
      int byte = col * 128 + (((p * 4 + g) ^ (col & 7)) << 4);
      b[n] = *(const bf16x8*)((const char*)slot + byte);
    }
#pragma unroll
    for (int n = 0; n < 2; ++n)
#pragma unroll
      for (int m = 0; m < 2; ++m)
        acc[m][n] = mfma16(a[m], b[n], acc[m][n]);
  }
}

// bias + relu + bf16 -> LDS [32][LDB] (swizzled).
template <int NREP, int LDB>
__device__ __forceinline__ void store_h2(short* xl, const float* __restrict__ bias,
                                         int wc, int lane, f32x4 acc[2][NREP]) {
  const int m0 = lane & 15;
  const int g = lane >> 4;
#pragma unroll
  for (int n = 0; n < NREP; ++n) {
    int col = wc * (NREP * 16) + n * 16 + m0;
    float bv = bias[col];
#pragma unroll
    for (int m = 0; m < 2; ++m) {
#pragma unroll
      for (int j = 0; j < 4; ++j) {
        int row = m * 16 + g * 4 + j;
        float v = acc[m][n][j] + bv;
        v = fmaxf(v, 0.f);
        int byte = row * LDB + col * 2;
        byte ^= (row & 7) << 4;
        *(short*)((char*)xl + byte) = f2bf(v);
      }
    }
  }
}

// acc -> LDS f32 [32][128] (swizzled) -> streaming full-row float4 stores + bf16 copy.
template <typename F>
__device__ __forceinline__ void coalesced_out(float* fl, const float* __restrict__ bias,
                                              int wc, int tid, int lane,
                                              f32x4 acc[2][2], float* __restrict__ gout,
                                              short* __restrict__ ecopy, F rowmap) {
  const int m0 = lane & 15;
  const int g = lane >> 4;
#pragma unroll
  for (int n = 0; n < 2; ++n) {
    int col = wc * 32 + n * 16 + m0;
    float bv = bias[col];
#pragma unroll
    for (int m = 0; m < 2; ++m) {
#pragma unroll
      for (int j = 0; j < 4; ++j) {
        int row = m * 16 + g * 4 + j;
        int byte = (row * 128 + col) * 4;
        byte ^= (row & 7) << 4;
        *(float*)((char*)fl + byte) = acc[m][n][j] + bv;
      }
    }
  }
  __syncthreads();
#pragma unroll
  for (int q = 0; q < 4; ++q) {
    int idx = q * 1024 + tid * 4;       // 32x128 floats, 256 threads
    int row = idx >> 7;
    long grow = rowmap(row);
    if (grow < 0) continue;
    int byte = (idx * 4) ^ ((row & 7) << 4);
    float4 v = *(const float4*)((const char*)fl + byte);
    *(float4*)(gout + grow * 128 + (idx & 127)) = v;
    if (ecopy) {
      short4v pk;
      pk[0] = f2bf(v.x); pk[1] = f2bf(v.y); pk[2] = f2bf(v.z); pk[3] = f2bf(v.w);
      *(short4v*)(ecopy + grow * 128 + (idx & 127)) = pk;
    }
  }
}

// Fused 3-layer edge MLP, 32-edge tile, 4 waves, ring-2 W slices through LDS.
// 52 KB LDS -> 3 blocks/CU; r12-proven stage discipline:
// issue(t+1) -> VMW4 -> BARX -> comp(t) -> BARX, sched_barrier(0) pins.
__global__ __launch_bounds__(256, 3) void edge_kernel(
    const short* __restrict__ nbf, const float* __restrict__ edge_attrs,
    const int* __restrict__ senders, const int* __restrict__ receivers,
    const short* __restrict__ wsw,
    const float* __restrict__ b0, const float* __restrict__ b1,
    const float* __restrict__ b2, float* __restrict__ e_out,
    short* __restrict__ ecopy) {
  __shared__ short lds[26624];             // 52 KB
  short* xl = lds;                         // X: [32][640B] bytes 0..20480; h: 0..16384
  short* p0 = lds + 10240;                 // slice slot 0: bytes 20480..36864
  short* p1 = lds + 18432;                 // slice slot 1: bytes 36864..53248
  const int tid = threadIdx.x;
  const int lane = tid & 63;
  const int wid = tid >> 6;                // 0..3 = wc
  const int e0 = blockIdx.x * 32;
  const short* w0t = wsw + OFF_FE_W0T;
  const short* w1t = wsw + OFF_FE_W1T;
  const short* w2t = wsw + OFF_FE_W2T;

  // prologue: W0 slice 0 flies under the gather
  stage256<320>(w0t, 0, p0, wid, lane);

  // ---- gather X = [ns(128)|nr(128)|ea(64)] bf16 [32][320], swizzled ----
#pragma unroll
  for (int i = 0; i < 5; ++i) {
    int task = i * 256 + tid;       // 1280 16B-chunks
    int row = task / 40;
    int c = task - row * 40;
    int erow = e0 + row;
    short8 pk;
    if (c < 32) {
      const short* p = (c < 16) ? nbf + (size_t)senders[erow] * 128 + c * 8
                                : nbf + (size_t)receivers[erow] * 128 + (c - 16) * 8;
      pk = *(const short8*)p;
    } else {
      const float* p = edge_attrs + (size_t)erow * 64 + (c - 32) * 8;
      float4 v0 = *(const float4*)p;
      float4 v1 = *(const float4*)(p + 4);
      pk[0] = f2bf(v0.x); pk[1] = f2bf(v0.y); pk[2] = f2bf(v0.z); pk[3] = f2bf(v0.w);
      pk[4] = f2bf(v1.x); pk[5] = f2bf(v1.y); pk[6] = f2bf(v1.z); pk[7] = f2bf(v1.w);
    }
    int byte = row * 640 + c * 16;
    byte ^= (row & 7) << 4;
    *(short8*)((char*)xl + byte) = pk;
  }
  __syncthreads();   // drains gather + slice0

  // ---- unified 22-stage pipeline: W0 t=0..9, W1 t=10..17, W2 t=18..21 ----
  f32x4 acc[2][4];
#pragma unroll
  for (int m = 0; m < 2; ++m)
#pragma unroll
    for (int n = 0; n < 4; ++n) acc[m][n] = (f32x4){0.f, 0.f, 0.f, 0.f};
  f32x4 acc2[2][2];
#pragma unroll
  for (int m = 0; m < 2; ++m)
#pragma unroll
    for (int n = 0; n < 2; ++n) acc2[m][n] = (f32x4){0.f, 0.f, 0.f, 0.f};

#pragma unroll
  for (int t = 0; t < 22; ++t) {
    // layer transitions (t literal -> folds): write h into dead X region.
    if (t == 10) {
      store_h2<4, 512>(xl, b0, wid, lane, acc);          // h0 <- L0 acc
      SBAR0; LKW0; SBAR0; BARX; SBAR0;
#pragma unroll
      for (int m = 0; m < 2; ++m)
#pragma unroll
        for (int n = 0; n < 4; ++n) acc[m][n] = (f32x4){0.f, 0.f, 0.f, 0.f};
    }
    if (t == 18) {
      store_h2<4, 512>(xl, b1, wid, lane, acc);          // h1 <- L1 acc
      SBAR0; LKW0; SBAR0; BARX; SBAR0;
    }
    // issue slice t+1 into slot (t+1)&1 (last read at comp(t-1); protected by
    // stage t-1's trailing barrier).
    if (t < 21) {
      const int u = t + 1;
      short* nxt = (u & 1) ? p1 : p0;
      if (u <= 9)       stage256<320>(w0t, u * 32, nxt, wid, lane);
      else if (u <= 17) stage256<256>(w1t, (u - 10) * 32, nxt, wid, lane);
      else              stage128(w2t, (u - 18) * 64, nxt, wid, lane);
    }
    SBAR0;
    if (t < 21) { VMW4; } else { VMW0; }   // slice t landed (in-order retirement)
    SBAR0; BARX; SBAR0;                    // ...for ALL waves
    const short* cur = (t & 1) ? p1 : p0;
    if (t < 10)      comp_step<4, 640>(xl, cur, t, wid, lane, acc);
    else if (t < 18) comp_step<4, 512>(xl, cur, t - 10, wid, lane, acc);
    else             comp_pairf<512>(xl, cur, (t - 18) * 2, wid, lane, acc2);
    SBAR0; BARX; SBAR0;                    // slot dead before reuse
  }

  coalesced_out((float*)lds, b2, wid, tid, lane, acc2, e_out, ecopy,
                [&](int row) -> long { return (long)(e0 + row); });
}

// ---------------- node kernel (unchanged from r12) ----------------
template <int KSTEPS, int MF, int NREP, int LDB, int WTK>
__device__ __forceinline__ void gemm_layer(const short* lds, const short* Wt,
                                           int wn, int lane, f32x4 acc[MF][NREP]) {
  const int m0 = lane & 15;
  const int g = lane >> 4;
  const short* wp = Wt + (wn * (NREP * 16) + m0) * WTK + g * 8;
  bf16x8 bcur[NREP], bnxt[NREP], a[MF];
#pragma unroll
  for (int n = 0; n < NREP; ++n) bcur[n] = *(const bf16x8*)(wp + n * 16 * WTK);
#pragma unroll
  for (int ks = 0; ks < KSTEPS; ++ks) {
    if (ks + 1 < KSTEPS) {
#pragma unroll
      for (int n = 0; n < NREP; ++n)
        bnxt[n] = *(const bf16x8*)(wp + (ks + 1) * 32 + n * 16 * WTK);
    }
    const int kb = ks * 32 + g * 8;
#pragma unroll
    for (int m = 0; m < MF; ++m) {
      int row = m * 16 + m0;
      int byte = row * LDB + kb * 2;
      byte ^= (row & 7) << 4;
      a[m] = *(const bf16x8*)((const char*)lds + byte);
    }
#pragma unroll
    for (int n = 0; n < NREP; ++n)
#pragma unroll
      for (int m = 0; m < MF; ++m)
        acc[m][n] = __builtin_amdgcn_mfma_f32_16x16x32_bf16(a[m], bcur[n], acc[m][n], 0, 0, 0);
#pragma unroll
    for (int n = 0; n < NREP; ++n) bcur[n] = bnxt[n];
  }
}

template <int MF, int NREP, int LDB>
__device__ __forceinline__ void store_h(short* lds, const float* __restrict__ bias,
                                        int wn, int lane, f32x4 acc[MF][NREP]) {
  const int m0 = lane & 15;
  const int g = lane >> 4;
#pragma unroll
  for (int n = 0; n < NREP; ++n) {
    int col = wn * (NREP * 16) + n * 16 + m0;
    float bv = bias[col];
#pragma unroll
    for (int m = 0; m < MF; ++m) {
#pragma unroll
      for (int j = 0; j < 4; ++j) {
        int row = m * 16 + g * 4 + j;
        float v = acc[m][n][j] + bv;
        v = fmaxf(v, 0.f);
        int byte = row * LDB + col * 2;
        byte ^= (row & 7) << 4;
        *(short*)((char*)lds + byte) = f2bf(v);
      }
    }
  }
}

__global__ __launch_bounds__(512, 4) void node_kernel(
    const short* __restrict__ nbf, const float* __restrict__ e_out,
    const short* __restrict__ ecopy,
    const int* __restrict__ basep, const int* __restrict__ eidx,
    const short* __restrict__ wsw,
    const float* __restrict__ b0, const float* __restrict__ b1,
    const float* __restrict__ b2, float* __restrict__ n_out) {
  __shared__ short lds[16384];  // 32 KiB
  const int tid = threadIdx.x;
  const int lane = tid & 63;
  const int wn = tid >> 6;
  const int r0 = blockIdx.x * 64;

#pragma unroll
  for (int i = 0; i < 2; ++i) {
    int task = i * 512 + tid;
    int row = task >> 4;
    int c = task & 15;
    int nrow = r0 + row;
    if (nrow >= NNODES) nrow = NNODES - 1;
    short8 pk = *(const short8*)(nbf + (size_t)nrow * 128 + c * 8);
    int byte = row * 512 + c * 16;
    byte ^= (row & 7) << 4;
    *(short8*)((char*)lds + byte) = pk;
  }

  {
    const int n_local = tid >> 3;
    const int cg = tid & 7;
    const int node = r0 + n_local;
    float sum[16];
#pragma unroll
    for (int q = 0; q < 16; ++q) sum[q] = 0.f;
    if (node < NNODES) {
      int beg = basep[node], end = basep[node + 1];
      if (ecopy) {
        for (int j = beg; j < end; ++j) {
          int e = eidx[j];
          const short8* er = (const short8*)(ecopy + (size_t)e * 128 + cg * 16);
          short8 v0 = er[0], v1 = er[1];
#pragma unroll
          for (int k = 0; k < 8; ++k) {
            sum[k] += bf2f(v0[k]);
            sum[8 + k] += bf2f(v1[k]);
          }
        }
      } else {
        for (int j = beg; j < end; ++j) {
          int e = eidx[j];
          const float* er = e_out + (size_t)e * 128 + cg * 16;
#pragma unroll
          for (int q = 0; q < 4; ++q) {
            float4 v = *(const float4*)(er + q * 4);
            sum[q * 4 + 0] += v.x; sum[q * 4 + 1] += v.y;
            sum[q * 4 + 2] += v.z; sum[q * 4 + 3] += v.w;
          }
        }
      }
    }
#pragma unroll
    for (int q = 0; q < 2; ++q) {
      short8 pk;
#pragma unroll
      for (int k = 0; k < 8; ++k) pk[k] = f2bf(sum[q * 8 + k]);
      int col = 128 + cg * 16 + q * 8;
      int byte = n_local * 512 + col * 2;
      byte ^= (n_local & 7) << 4;
      *(short8*)((char*)lds + byte) = pk;
    }
  }
  __syncthreads();

  f32x4 acc[4][2];
#pragma unroll
  for (int m = 0; m < 4; ++m)
#pragma unroll
    for (int n = 0; n < 2; ++n) acc[m][n] = (f32x4){0.f, 0.f, 0.f, 0.f};
  gemm_layer<8, 4, 2, 512, 256>(lds, wsw + OFF_FN_W0T, wn, lane, acc);
  __syncthreads();
  store_h<4, 2, 512>(lds, b0, wn, lane, acc);
  __syncthreads();

#pragma unroll
  for (int m = 0; m < 4; ++m)
#pragma unroll
    for (int n = 0; n < 2; ++n) acc[m][n] = (f32x4){0.f, 0.f, 0.f, 0.f};
  gemm_layer<8, 4, 2, 512, 256>(lds, wsw + OFF_FN_W1T, wn, lane, acc);
  __syncthreads();
  store_h<4, 2, 512>(lds, b1, wn, lane, acc);
  __syncthreads();

  f32x4 acc2[4][1];
#pragma unroll
  for (int m = 0; m < 4; ++m) acc2[m][0] = (f32x4){0.f, 0.f, 0.f, 0.f};
  gemm_layer<8, 4, 1, 512, 256>(lds, wsw + OFF_FN_W2T, wn, lane, acc2);
  __syncthreads();

  {
    float* fl = (float*)lds;
    const int m0 = lane & 15;
    const int g = lane >> 4;
    int col = wn * 16 + m0;
    float bv = b2[col];
#pragma unroll
    for (int m = 0; m < 4; ++m) {
#pragma unroll
      for (int j = 0; j < 4; ++j) {
        int row = m * 16 + g * 4 + j;
        int byte = (row * 128 + col) * 4;
        byte ^= (row & 7) << 4;
        *(float*)((char*)fl + byte) = acc2[m][0][j] + bv;
      }
    }
    __syncthreads();
#pragma unroll
    for (int q = 0; q < 4; ++q) {
      int idx = q * 2048 + tid * 4;
      int row = idx >> 7;
      long grow = r0 + row;
      if (grow >= NNODES) continue;
      int byte = (idx * 4) ^ ((row & 7) << 4);
      float4 v = *(const float4*)((const char*)fl + byte);
      *(float4*)(n_out + grow * 128 + (idx & 127)) = v;
    }
  }
}

// ---------------- prep / CSR (unchanged) ----------------
__global__ void prep_weights_all(const float* __restrict__ w0, const float* __restrict__ w1,
                                 const float* __restrict__ w2, const float* __restrict__ w3,
                                 const float* __restrict__ w4, const float* __restrict__ w5,
                                 short* __restrict__ wsw) {
  const float* src; short* dst; int K, N;
  switch (blockIdx.y) {
    case 0: src = w0; dst = wsw + OFF_FE_W0T; K = 320; N = 256; break;
    case 1: src = w1; dst = wsw + OFF_FE_W1T; K = 256; N = 256; break;
    case 2: src = w2; dst = wsw + OFF_FE_W2T; K = 256; N = 128; break;
    case 3: src = w3; dst = wsw + OFF_FN_W0T; K = 256; N = 256; break;
    case 4: src = w4; dst = wsw + OFF_FN_W1T; K = 256; N = 256; break;
    default: src = w5; dst = wsw + OFF_FN_W2T; K = 256; N = 128; break;
  }
  int idx = blockIdx.x * 256 + threadIdx.x;
  if (idx < K * N) {
    int k = idx / N;
    int n = idx - k * N;
    dst[n * K + k] = f2bf(src[idx]);
  }
}

__global__ void cvt_bf16(const float* __restrict__ src, short* __restrict__ dst, int n8) {
  int i = blockIdx.x * 256 + threadIdx.x;
  if (i < n8) {
    float4 v0 = ((const float4*)src)[i * 2];
    float4 v1 = ((const float4*)src)[i * 2 + 1];
    short8 pk;
    pk[0] = f2bf(v0.x); pk[1] = f2bf(v0.y); pk[2] = f2bf(v0.z); pk[3] = f2bf(v0.w);
    pk[4] = f2bf(v1.x); pk[5] = f2bf(v1.y); pk[6] = f2bf(v1.z); pk[7] = f2bf(v1.w);
    ((short8*)dst)[i] = pk;
  }
}

__global__ void hist_kernel(const int* __restrict__ receivers, int* __restrict__ cnt) {
  int e = blockIdx.x * 512 + threadIdx.x;
  if (e < NEDGES) atomicAdd(&cnt[receivers[e]], 1);
}

__global__ __launch_bounds__(1024) void scan1_kernel(const int* __restrict__ cnt,
                                                     int* __restrict__ base,
                                                     int* __restrict__ bsum) {
  __shared__ int s[1024];
  const int tid = threadIdx.x;
  int i = blockIdx.x * 1024 + tid;
  int v = (i < NNODES) ? cnt[i] : 0;
  s[tid] = v;
  __syncthreads();
  for (int off = 1; off < 1024; off <<= 1) {
    int t = (tid >= off) ? s[tid - off] : 0;
    __syncthreads();
    s[tid] += t;
    __syncthreads();
  }
  if (i < NNODES) base[i] = s[tid] - v;
  if (tid == 1023) bsum[blockIdx.x] = s[1023];
}

__global__ void scan2_kernel(int* __restrict__ bsum, int nblk) {
  if (threadIdx.x == 0) {
    int run = 0;
    for (int b = 0; b < nblk; ++b) { int t = bsum[b]; bsum[b] = run; run += t; }
  }
}

__global__ __launch_bounds__(1024) void scan3_kernel(const int* __restrict__ bsum,
                                                     int* __restrict__ base,
                                                     int* __restrict__ cursor) {
  int i = blockIdx.x * 1024 + threadIdx.x;
  if (i < NNODES) {
    int b = base[i] + bsum[blockIdx.x];
    base[i] = b;
    cursor[i] = b;
  }
  if (i == 0) base[NNODES] = NEDGES;
}

__global__ void scatter_kernel(const int* __restrict__ receivers, int* __restrict__ cursor,
                               int* __restrict__ eidx) {
  int e = blockIdx.x * 512 + threadIdx.x;
  if (e < NEDGES) {
    int pos = atomicAdd(&cursor[receivers[e]], 1);
    eidx[pos] = e;
  }
}

extern "C" void kernel_launch(void* const* d_in, const int* in_sizes, int n_in,
                              void* d_out, int out_size, void* d_ws, size_t ws_size,
                              hipStream_t stream) {
  const float* node_attrs = (const float*)d_in[0];
  const float* edge_attrs = (const float*)d_in[1];
  const int* senders = (const int*)d_in[2];
  const int* receivers = (const int*)d_in[3];
  const float* fe_W0 = (const float*)d_in[4];
  const float* fe_b0 = (const float*)d_in[5];
  const float* fe_W1 = (const float*)d_in[6];
  const float* fe_b1 = (const float*)d_in[7];
  const float* fe_W2 = (const float*)d_in[8];
  const float* fe_b2 = (const float*)d_in[9];
  const float* fn_W0 = (const float*)d_in[10];
  const float* fn_b0 = (const float*)d_in[11];
  const float* fn_W1 = (const float*)d_in[12];
  const float* fn_b1 = (const float*)d_in[13];
  const float* fn_W2 = (const float*)d_in[14];
  const float* fn_b2 = (const float*)d_in[15];

  short* wsw  = (short*)d_ws;
  int* cnt    = (int*)((char*)d_ws + OFF_CNT_B);
  int* basep  = (int*)((char*)d_ws + OFF_BASE_B);
  int* cursor = (int*)((char*)d_ws + OFF_CURSOR_B);
  int* eidx   = (int*)((char*)d_ws + OFF_EIDX_B);
  int* bsum   = (int*)((char*)d_ws + OFF_BSUM_B);
  short* nbf  = (short*)((char*)d_ws + OFF_NBF_B);
  short* ecopy = (ws_size >= ECOPY_NEED) ? (short*)((char*)d_ws + OFF_ECOPY_B) : nullptr;
  float* out = (float*)d_out;
  float* n_out = out;                                  // [50000][128] first
  float* e_out = out + (size_t)NNODES * 128;           // then [800000][128]

  dim3 gprep(320, 6);
  prep_weights_all<<<gprep, 256, 0, stream>>>(fe_W0, fe_W1, fe_W2, fn_W0, fn_W1, fn_W2, wsw);
  cvt_bf16<<<(NNODES * 128 / 8 + 255) / 256, 256, 0, stream>>>(node_attrs, nbf, NNODES * 128 / 8);
  hipMemsetAsync(cnt, 0, NNODES * sizeof(int), stream);

  const int nscan = (NNODES + 1023) / 1024;   // 49
  hist_kernel<<<(NEDGES + 511) / 512, 512, 0, stream>>>(receivers, cnt);
  scan1_kernel<<<nscan, 1024, 0, stream>>>(cnt, basep, bsum);
  scan2_kernel<<<1, 64, 0, stream>>>(bsum, nscan);
  scan3_kernel<<<nscan, 1024, 0, stream>>>(bsum, basep, cursor);
  scatter_kernel<<<(NEDGES + 511) / 512, 512, 0, stream>>>(receivers, cursor, eidx);

  edge_kernel<<<NEDGES / 32, 256, 0, stream>>>(nbf, edge_attrs, senders, receivers,
                                               wsw, fe_b0, fe_b1, fe_b2, e_out, ecopy);
  node_kernel<<<(NNODES + 63) / 64, 512, 0, stream>>>(nbf, e_out, ecopy, basep, eidx, wsw,
                                                      fn_b0, fn_b1, fn_b2, n_out);
}

// Round 14
// 727.376 us; speedup vs baseline: 2.8436x; 2.8436x over previous
//
#include <hip/hip_runtime.h>

#define NNODES 50000
#define NEDGES 800000

typedef __bf16 bf16x8 __attribute__((ext_vector_type(8)));
typedef short short8 __attribute__((ext_vector_type(8)));
typedef short short4v __attribute__((ext_vector_type(4)));
typedef float f32x4 __attribute__((ext_vector_type(4)));

// ws layout (byte offsets):
#define OFF_FE_W0T 0        // short idx
#define OFF_FE_W1T 81920
#define OFF_FE_W2T 147456
#define OFF_FN_W0T 180224
#define OFF_FN_W1T 245760
#define OFF_FN_W2T 311296   // ends at short 344064 = byte 688128
#define OFF_CNT_B    688128              // int[50000]
#define OFF_BASE_B   888128              // int[50001]
#define OFF_CURSOR_B 1088384             // int[50000]
#define OFF_EIDX_B   1288448             // int[800000]
#define OFF_BSUM_B   4488448             // int[64]
#define OFF_NBF_B    4488704             // short[50000*128] bf16 node table (12.8 MB)
#define OFF_Y_B      17288704            // short[50000*512] bf16 Y=na*W0[0:256] (51.2 MB)
#define OFF_ECOPY_B  68488704            // short[800000*128] bf16 e_out copy (204.8 MB)
#define ECOPY_NEED   (68488704ull + 204800000ull)

__device__ __forceinline__ short f2bf(float f) {
  union { float f; unsigned u; } v; v.f = f;
  unsigned r = v.u + 0x7FFFu + ((v.u >> 16) & 1u);   // RNE
  return (short)(r >> 16);
}
__device__ __forceinline__ float bf2f(short s) {
  union { unsigned u; float f; } v; v.u = ((unsigned)(unsigned short)s) << 16;
  return v.f;
}

typedef const unsigned __attribute__((address_space(1)))* gas_t;
typedef unsigned __attribute__((address_space(3)))* las_t;
__device__ __forceinline__ void gload16(const short* g, short* l) {
  __builtin_amdgcn_global_load_lds((gas_t)(const void*)g, (las_t)(void*)l, 16, 0, 0);
}

#define VMW2 asm volatile("s_waitcnt vmcnt(2)" ::: "memory")
#define VMW0 asm volatile("s_waitcnt vmcnt(0)" ::: "memory")
#define LKW0 asm volatile("s_waitcnt lgkmcnt(0)" ::: "memory")
#define BARX __builtin_amdgcn_s_barrier()
#define SBAR0 __builtin_amdgcn_sched_barrier(0)

__device__ __forceinline__ f32x4 mfma16(bf16x8 a, bf16x8 b, f32x4 c) {
  return __builtin_amdgcn_mfma_f32_16x16x32_bf16(a, b, c, 0, 0, 0);
}

// 256-row, 1-K-step slice (16KB): [256 rows][64B]; chunk sl of row r holds
// W[r][kbase + ((sl^((r>>1)&3))*8) .. +8]. Linear gload dest; swizzled read.
template <int WTK>
__device__ __forceinline__ void stage256(const short* __restrict__ Wt, int kbase,
                                         short* slot, int wid, int lane) {
#pragma unroll
  for (int r = 0; r < 2; ++r) {
    int f = (r * 8 + wid) * 64 + lane;
    int row = f >> 2;
    int sl = f & 3;
    int sig = (row >> 1) & 3;
    const short* src = Wt + row * WTK + kbase + ((sl ^ sig) << 3);
    short* dst = slot + (r * 8 + wid) * 512;
    gload16(src, dst);
  }
}

// 128-row, 2-K-step slice (16KB): [128 rows][128B]; chunk sl of row r holds
// W[r][kbase + ((sl^(r&7))*8) .. +8].
__device__ __forceinline__ void stage128(const short* __restrict__ Wt, int kbase,
                                         short* slot, int wid, int lane) {
#pragma unroll
  for (int r = 0; r < 2; ++r) {
    int f = (r * 8 + wid) * 64 + lane;
    int row = f >> 3;
    int sl = f & 7;
    const short* src = Wt + row * 256 + kbase + ((sl ^ (row & 7)) << 3);
    short* dst = slot + (r * 8 + wid) * 512;
    gload16(src, dst);
  }
}

// One K-step, A from LDS tile (64 rows, MF=2), B from 256-row slice.
template <int NREP, int LDB>
__device__ __forceinline__ void comp_step(const short* xl, const short* slot, int kk,
                                          int wr, int wc, int lane, f32x4 acc[2][NREP]) {
  const int m0 = lane & 15;
  const int g = lane >> 4;
  bf16x8 a[2], b[NREP];
#pragma unroll
  for (int m = 0; m < 2; ++m) {
    int row = wr * 32 + m * 16 + m0;
    int byte = row * LDB + kk * 64 + g * 16;
    byte ^= (row & 7) << 4;
    a[m] = *(const bf16x8*)((const char*)xl + byte);
  }
#pragma unroll
  for (int n = 0; n < NREP; ++n) {
    int col = wc * (NREP * 16) + n * 16 + m0;
    int byte = col * 64 + ((g ^ ((col >> 1) & 3)) << 4);
    b[n] = *(const bf16x8*)((const char*)slot + byte);
  }
#pragma unroll
  for (int n = 0; n < NREP; ++n)
#pragma unroll
    for (int m = 0; m < 2; ++m)
      acc[m][n] = mfma16(a[m], b[n], acc[m][n]);
}

// Two K-steps against a 128-row slice (final layer, NREP=2).
template <int LDB>
__device__ __forceinline__ void comp_pairf(const short* xl, const short* slot, int kk0,
                                           int wr, int wc, int lane, f32x4 acc[2][2]) {
  const int m0 = lane & 15;
  const int g = lane >> 4;
#pragma unroll
  for (int p = 0; p < 2; ++p) {
    const int kk = kk0 + p;
    bf16x8 a[2], b[2];
#pragma unroll
    for (int m = 0; m < 2; ++m) {
      int row = wr * 32 + m * 16 + m0;
      int byte = row * LDB + kk * 64 + g * 16;
      byte ^= (row & 7) << 4;
      a[m] = *(const bf16x8*)((const char*)xl + byte);
    }
#pragma unroll
    for (int n = 0; n < 2; ++n) {
      int col = wc * 32 + n * 16 + m0;
      int byte = col * 128 + (((p * 4 + g) ^ (col & 7)) << 4);
      b[n] = *(const bf16x8*)((const char*)slot + byte);
    }
#pragma unroll
    for (int n = 0; n < 2; ++n)
#pragma unroll
      for (int m = 0; m < 2; ++m)
        acc[m][n] = mfma16(a[m], b[n], acc[m][n]);
  }
}

// bias + relu + bf16 -> LDS [64][LDB] (swizzled).
template <int NREP, int LDB>
__device__ __forceinline__ void store_h2(short* xl, const float* __restrict__ bias,
                                         int wr, int wc, int lane, f32x4 acc[2][NREP]) {
  const int m0 = lane & 15;
  const int g = lane >> 4;
#pragma unroll
  for (int n = 0; n < NREP; ++n) {
    int col = wc * (NREP * 16) + n * 16 + m0;
    float bv = bias[col];
#pragma unroll
    for (int m = 0; m < 2; ++m) {
#pragma unroll
      for (int j = 0; j < 4; ++j) {
        int row = wr * 32 + m * 16 + g * 4 + j;
        float v = acc[m][n][j] + bv;
        v = fmaxf(v, 0.f);
        int byte = row * LDB + col * 2;
        byte ^= (row & 7) << 4;
        *(short*)((char*)xl + byte) = f2bf(v);
      }
    }
  }
}

// h0 = relu(Ysum(in-place) + acc + b0). Each thread reads/writes only its own cells.
__device__ __forceinline__ void store_h0_add(short* xl, const float* __restrict__ bias,
                                             int wr, int wc, int lane, f32x4 acc[2][4]) {
  const int m0 = lane & 15;
  const int g = lane >> 4;
#pragma unroll
  for (int n = 0; n < 4; ++n) {
    int col = wc * 64 + n * 16 + m0;
    float bv = bias[col];
#pragma unroll
    for (int m = 0; m < 2; ++m) {
#pragma unroll
      for (int j = 0; j < 4; ++j) {
        int row = wr * 32 + m * 16 + g * 4 + j;
        int byte = row * 512 + col * 2;
        byte ^= (row & 7) << 4;
        short* p = (short*)((char*)xl + byte);
        float v = acc[m][n][j] + bv + bf2f(*p);
        *p = f2bf(fmaxf(v, 0.f));
      }
    }
  }
}

// acc -> LDS f32 [64][128] (swizzled) -> streaming full-row float4 stores (+bf16 ecopy).
template <typename F>
__device__ __forceinline__ void coalesced_out(float* fl, const float* __restrict__ bias,
                                              int wr, int wc, int tid, int lane,
                                              f32x4 acc[2][2], float* __restrict__ gout,
                                              short* __restrict__ ecopy, F rowmap) {
  const int m0 = lane & 15;
  const int g = lane >> 4;
#pragma unroll
  for (int n = 0; n < 2; ++n) {
    int col = wc * 32 + n * 16 + m0;
    float bv = bias[col];
#pragma unroll
    for (int m = 0; m < 2; ++m) {
#pragma unroll
      for (int j = 0; j < 4; ++j) {
        int row = wr * 32 + m * 16 + g * 4 + j;
        int byte = (row * 128 + col) * 4;
        byte ^= (row & 7) << 4;
        *(float*)((char*)fl + byte) = acc[m][n][j] + bv;
      }
    }
  }
  __syncthreads();
#pragma unroll
  for (int q = 0; q < 4; ++q) {
    int idx = q * 2048 + tid * 4;       // 64x128 floats, 512 threads
    int row = idx >> 7;
    long grow = rowmap(row);
    if (grow < 0) continue;
    int byte = (idx * 4) ^ ((row & 7) << 4);
    float4 v = *(const float4*)((const char*)fl + byte);
    *(float4*)(gout + grow * 128 + (idx & 127)) = v;
    if (ecopy) {
      short4v pk;
      pk[0] = f2bf(v.x); pk[1] = f2bf(v.y); pk[2] = f2bf(v.z); pk[3] = f2bf(v.w);
      *(short4v*)(ecopy + grow * 128 + (idx & 127)) = pk;
    }
  }
}

// Fused edge MLP with precomputed node terms: h0 = relu(Ys[s]+Yr[r] + ea*W0e + b0).
// 64-edge tile, 8 waves (2x4). 14 stages (ea:2, L1:8, Lf:4), ring-2 slices,
// r12-proven discipline: issue -> counted VMW -> BARX -> comp -> BARX, SBAR0 pins.
__global__ __launch_bounds__(512, 4) void edge_kernel(
    const short* __restrict__ Yt, const float* __restrict__ edge_attrs,
    const int* __restrict__ senders, const int* __restrict__ receivers,
    const short* __restrict__ wsw,
    const float* __restrict__ b0, const float* __restrict__ b1,
    const float* __restrict__ b2, float* __restrict__ e_out,
    short* __restrict__ ecopy) {
  __shared__ short lds[36864];             // 72 KB -> 2 blocks/CU
  short* xl = lds;                         // Ysum/h: [64][512B] bytes 0..32768
  short* eal = lds + 16384;                // ea: [64][128B] bytes 32768..40960
  short* p0 = lds + 20480;                 // slice slot 0: bytes 40960..57344
  short* p1 = lds + 28672;                 // slice slot 1: bytes 57344..73728
  const int tid = threadIdx.x;
  const int lane = tid & 63;
  const int wid = tid >> 6;
  const int wr = wid >> 2, wc = wid & 3;
  const int e0 = blockIdx.x * 64;
  const short* w0t = wsw + OFF_FE_W0T;
  const short* w1t = wsw + OFF_FE_W1T;
  const short* w2t = wsw + OFF_FE_W2T;

  // prologue: W0e slice 0 (kbase 256) flies under the gather
  stage256<320>(w0t, 256, p0, wid, lane);

  // ---- gather Ysum = Ys[send] + Yr[recv] -> xl [64][256] bf16 swizzled ----
#pragma unroll
  for (int i = 0; i < 4; ++i) {
    int task = i * 512 + tid;       // 2048 chunks (64 rows x 32)
    int row = task >> 5;
    int c = task & 31;
    int erow = e0 + row;
    short8 vs = *(const short8*)(Yt + (size_t)senders[erow] * 512 + c * 8);
    short8 vr = *(const short8*)(Yt + (size_t)receivers[erow] * 512 + 256 + c * 8);
    short8 pk;
#pragma unroll
    for (int k = 0; k < 8; ++k) pk[k] = f2bf(bf2f(vs[k]) + bf2f(vr[k]));
    int byte = row * 512 + c * 16;
    byte ^= (row & 7) << 4;
    *(short8*)((char*)xl + byte) = pk;
  }
  // ---- stage ea -> eal [64][64] bf16 swizzled (LDB=128) ----
  {
    int row = tid >> 3;             // 512 tasks (64 rows x 8)
    int c = tid & 7;
    const float* p = edge_attrs + (size_t)(e0 + row) * 64 + c * 8;
    float4 v0 = *(const float4*)p;
    float4 v1 = *(const float4*)(p + 4);
    short8 pk;
    pk[0] = f2bf(v0.x); pk[1] = f2bf(v0.y); pk[2] = f2bf(v0.z); pk[3] = f2bf(v0.w);
    pk[4] = f2bf(v1.x); pk[5] = f2bf(v1.y); pk[6] = f2bf(v1.z); pk[7] = f2bf(v1.w);
    int byte = row * 128 + c * 16;
    byte ^= (row & 7) << 4;
    *(short8*)((char*)eal + byte) = pk;
  }
  __syncthreads();   // drains gather + slice0

  // ---- 14-stage pipeline: ea t=0..1, L1 t=2..9, Lf t=10..13 ----
  f32x4 acc[2][4];
#pragma unroll
  for (int m = 0; m < 2; ++m)
#pragma unroll
    for (int n = 0; n < 4; ++n) acc[m][n] = (f32x4){0.f, 0.f, 0.f, 0.f};
  f32x4 acc2[2][2];
#pragma unroll
  for (int m = 0; m < 2; ++m)
#pragma unroll
    for (int n = 0; n < 2; ++n) acc2[m][n] = (f32x4){0.f, 0.f, 0.f, 0.f};

#pragma unroll
  for (int t = 0; t < 14; ++t) {
    if (t == 2) {   // h0 = relu(Ysum + acc + b0), in place (after t=1's trailing BARX)
      store_h0_add(xl, b0, wr, wc, lane, acc);
      SBAR0; LKW0; SBAR0; BARX; SBAR0;
#pragma unroll
      for (int m = 0; m < 2; ++m)
#pragma unroll
        for (int n = 0; n < 4; ++n) acc[m][n] = (f32x4){0.f, 0.f, 0.f, 0.f};
    }
    if (t == 10) {  // h1 (after t=9's trailing BARX)
      store_h2<4, 512>(xl, b1, wr, wc, lane, acc);
      SBAR0; LKW0; SBAR0; BARX; SBAR0;
    }
    if (t < 13) {
      const int u = t + 1;
      short* nxt = (u & 1) ? p1 : p0;
      if (u <= 1)      stage256<320>(w0t, 256 + u * 32, nxt, wid, lane);
      else if (u <= 9) stage256<256>(w1t, (u - 2) * 32, nxt, wid, lane);
      else             stage128(w2t, (u - 10) * 64, nxt, wid, lane);
    }
    SBAR0;
    if (t < 13) { VMW2; } else { VMW0; }
    SBAR0; BARX; SBAR0;
    const short* cur = (t & 1) ? p1 : p0;
    if (t < 2)       comp_step<4, 128>(eal, cur, t, wr, wc, lane, acc);
    else if (t < 10) comp_step<4, 512>(xl, cur, t - 2, wr, wc, lane, acc);
    else             comp_pairf<512>(xl, cur, (t - 10) * 2, wr, wc, lane, acc2);
    SBAR0; BARX; SBAR0;
  }

  coalesced_out((float*)lds, b2, wr, wc, tid, lane, acc2, e_out, ecopy,
                [&](int row) -> long { return (long)(e0 + row); });
}

// ---------------- shared GEMM helpers (node + yprep) ----------------
template <int KSTEPS, int MF, int NREP, int LDB, int WTK>
__device__ __forceinline__ void gemm_layer(const short* lds, const short* Wt,
                                           int wn, int lane, f32x4 acc[MF][NREP]) {
  const int m0 = lane & 15;
  const int g = lane >> 4;
  const short* wp = Wt + (wn * (NREP * 16) + m0) * WTK + g * 8;
  bf16x8 bcur[NREP], bnxt[NREP], a[MF];
#pragma unroll
  for (int n = 0; n < NREP; ++n) bcur[n] = *(const bf16x8*)(wp + n * 16 * WTK);
#pragma unroll
  for (int ks = 0; ks < KSTEPS; ++ks) {
    if (ks + 1 < KSTEPS) {
#pragma unroll
      for (int n = 0; n < NREP; ++n)
        bnxt[n] = *(const bf16x8*)(wp + (ks + 1) * 32 + n * 16 * WTK);
    }
    const int kb = ks * 32 + g * 8;
#pragma unroll
    for (int m = 0; m < MF; ++m) {
      int row = m * 16 + m0;
      int byte = row * LDB + kb * 2;
      byte ^= (row & 7) << 4;
      a[m] = *(const bf16x8*)((const char*)lds + byte);
    }
#pragma unroll
    for (int n = 0; n < NREP; ++n)
#pragma unroll
      for (int m = 0; m < MF; ++m)
        acc[m][n] = __builtin_amdgcn_mfma_f32_16x16x32_bf16(a[m], bcur[n], acc[m][n], 0, 0, 0);
#pragma unroll
    for (int n = 0; n < NREP; ++n) bcur[n] = bnxt[n];
  }
}

template <int MF, int NREP, int LDB>
__device__ __forceinline__ void store_h(short* lds, const float* __restrict__ bias,
                                        int wn, int lane, f32x4 acc[MF][NREP]) {
  const int m0 = lane & 15;
  const int g = lane >> 4;
#pragma unroll
  for (int n = 0; n < NREP; ++n) {
    int col = wn * (NREP * 16) + n * 16 + m0;
    float bv = bias[col];
#pragma unroll
    for (int m = 0; m < MF; ++m) {
#pragma unroll
      for (int j = 0; j < 4; ++j) {
        int row = m * 16 + g * 4 + j;
        float v = acc[m][n][j] + bv;
        v = fmaxf(v, 0.f);
        int byte = row * LDB + col * 2;
        byte ^= (row & 7) << 4;
        *(short*)((char*)lds + byte) = f2bf(v);
      }
    }
  }
}

// Y[n] = na[n] * W0[0:256]  (bf16 in, f32 acc, bf16 out). 64-node tiles, 8 waves.
__global__ __launch_bounds__(512, 2) void yprep_kernel(
    const short* __restrict__ nbf, const short* __restrict__ w0t,
    short* __restrict__ Y) {
  __shared__ short lds[40960];  // xs 16KB + yl 64KB = 80KB
  short* xs = lds;              // [64][128] bf16, LDB=256, swizzled
  short* yl = lds + 8192;       // [64][512] bf16, linear
  const int tid = threadIdx.x;
  const int lane = tid & 63;
  const int wn = tid >> 6;      // 0..7
  const int n0 = blockIdx.x * 64;

#pragma unroll
  for (int i = 0; i < 2; ++i) {
    int task = i * 512 + tid;   // 1024 chunks
    int row = task >> 4;
    int c = task & 15;
    int nrow = n0 + row;
    if (nrow >= NNODES) nrow = NNODES - 1;
    short8 pk = *(const short8*)(nbf + (size_t)nrow * 128 + c * 8);
    int byte = row * 256 + c * 16;
    byte ^= (row & 7) << 4;
    *(short8*)((char*)xs + byte) = pk;
  }
  __syncthreads();

  // wave wn: cols (wn&3)*64 of {Ys if wn<4 (K 0..127) else Yr (K 128..255)}
  f32x4 acc[4][4];
#pragma unroll
  for (int m = 0; m < 4; ++m)
#pragma unroll
    for (int n = 0; n < 4; ++n) acc[m][n] = (f32x4){0.f, 0.f, 0.f, 0.f};
  gemm_layer<4, 4, 4, 256, 320>(xs, w0t + (wn >> 2) * 128, wn & 3, lane, acc);

  // acc -> yl linear [64][512]
  const int m0 = lane & 15;
  const int g = lane >> 4;
  const int colbase = (wn & 3) * 64 + (wn >> 2) * 256;
#pragma unroll
  for (int n = 0; n < 4; ++n) {
    int col = colbase + n * 16 + m0;
#pragma unroll
    for (int m = 0; m < 4; ++m)
#pragma unroll
      for (int j = 0; j < 4; ++j) {
        int row = m * 16 + g * 4 + j;
        yl[row * 512 + col] = f2bf(acc[m][n][j]);
      }
  }
  __syncthreads();

#pragma unroll
  for (int i = 0; i < 8; ++i) {
    int idx = i * 512 + tid;    // 4096 chunks
    int row = idx >> 6;
    int c = idx & 63;
    int nrow = n0 + row;
    if (nrow >= NNODES) continue;
    *(short8*)(Y + (size_t)nrow * 512 + c * 8) = *(const short8*)(yl + row * 512 + c * 8);
  }
}

// ---------------- node kernel (unchanged from r12) ----------------
__global__ __launch_bounds__(512, 4) void node_kernel(
    const short* __restrict__ nbf, const float* __restrict__ e_out,
    const short* __restrict__ ecopy,
    const int* __restrict__ basep, const int* __restrict__ eidx,
    const short* __restrict__ wsw,
    const float* __restrict__ b0, const float* __restrict__ b1,
    const float* __restrict__ b2, float* __restrict__ n_out) {
  __shared__ short lds[16384];  // 32 KiB
  const int tid = threadIdx.x;
  const int lane = tid & 63;
  const int wn = tid >> 6;
  const int r0 = blockIdx.x * 64;

#pragma unroll
  for (int i = 0; i < 2; ++i) {
    int task = i * 512 + tid;
    int row = task >> 4;
    int c = task & 15;
    int nrow = r0 + row;
    if (nrow >= NNODES) nrow = NNODES - 1;
    short8 pk = *(const short8*)(nbf + (size_t)nrow * 128 + c * 8);
    int byte = row * 512 + c * 16;
    byte ^= (row & 7) << 4;
    *(short8*)((char*)lds + byte) = pk;
  }

  {
    const int n_local = tid >> 3;
    const int cg = tid & 7;
    const int node = r0 + n_local;
    float sum[16];
#pragma unroll
    for (int q = 0; q < 16; ++q) sum[q] = 0.f;
    if (node < NNODES) {
      int beg = basep[node], end = basep[node + 1];
      if (ecopy) {
        for (int j = beg; j < end; ++j) {
          int e = eidx[j];
          const short8* er = (const short8*)(ecopy + (size_t)e * 128 + cg * 16);
          short8 v0 = er[0], v1 = er[1];
#pragma unroll
          for (int k = 0; k < 8; ++k) {
            sum[k] += bf2f(v0[k]);
            sum[8 + k] += bf2f(v1[k]);
          }
        }
      } else {
        for (int j = beg; j < end; ++j) {
          int e = eidx[j];
          const float* er = e_out + (size_t)e * 128 + cg * 16;
#pragma unroll
          for (int q = 0; q < 4; ++q) {
            float4 v = *(const float4*)(er + q * 4);
            sum[q * 4 + 0] += v.x; sum[q * 4 + 1] += v.y;
            sum[q * 4 + 2] += v.z; sum[q * 4 + 3] += v.w;
          }
        }
      }
    }
#pragma unroll
    for (int q = 0; q < 2; ++q) {
      short8 pk;
#pragma unroll
      for (int k = 0; k < 8; ++k) pk[k] = f2bf(sum[q * 8 + k]);
      int col = 128 + cg * 16 + q * 8;
      int byte = n_local * 512 + col * 2;
      byte ^= (n_local & 7) << 4;
      *(short8*)((char*)lds + byte) = pk;
    }
  }
  __syncthreads();

  f32x4 acc[4][2];
#pragma unroll
  for (int m = 0; m < 4; ++m)
#pragma unroll
    for (int n = 0; n < 2; ++n) acc[m][n] = (f32x4){0.f, 0.f, 0.f, 0.f};
  gemm_layer<8, 4, 2, 512, 256>(lds, wsw + OFF_FN_W0T, wn, lane, acc);
  __syncthreads();
  store_h<4, 2, 512>(lds, b0, wn, lane, acc);
  __syncthreads();

#pragma unroll
  for (int m = 0; m < 4; ++m)
#pragma unroll
    for (int n = 0; n < 2; ++n) acc[m][n] = (f32x4){0.f, 0.f, 0.f, 0.f};
  gemm_layer<8, 4, 2, 512, 256>(lds, wsw + OFF_FN_W1T, wn, lane, acc);
  __syncthreads();
  store_h<4, 2, 512>(lds, b1, wn, lane, acc);
  __syncthreads();

  f32x4 acc2[4][1];
#pragma unroll
  for (int m = 0; m < 4; ++m) acc2[m][0] = (f32x4){0.f, 0.f, 0.f, 0.f};
  gemm_layer<8, 4, 1, 512, 256>(lds, wsw + OFF_FN_W2T, wn, lane, acc2);
  __syncthreads();

  {
    float* fl = (float*)lds;
    const int m0 = lane & 15;
    const int g = lane >> 4;
    int col = wn * 16 + m0;
    float bv = b2[col];
#pragma unroll
    for (int m = 0; m < 4; ++m) {
#pragma unroll
      for (int j = 0; j < 4; ++j) {
        int row = m * 16 + g * 4 + j;
        int byte = (row * 128 + col) * 4;
        byte ^= (row & 7) << 4;
        *(float*)((char*)fl + byte) = acc2[m][0][j] + bv;
      }
    }
    __syncthreads();
#pragma unroll
    for (int q = 0; q < 4; ++q) {
      int idx = q * 2048 + tid * 4;
      int row = idx >> 7;
      long grow = r0 + row;
      if (grow >= NNODES) continue;
      int byte = (idx * 4) ^ ((row & 7) << 4);
      float4 v = *(const float4*)((const char*)fl + byte);
      *(float4*)(n_out + grow * 128 + (idx & 127)) = v;
    }
  }
}

// ---------------- prep / CSR (unchanged) ----------------
__global__ void prep_weights_all(const float* __restrict__ w0, const float* __restrict__ w1,
                                 const float* __restrict__ w2, const float* __restrict__ w3,
                                 const float* __restrict__ w4, const float* __restrict__ w5,
                                 short* __restrict__ wsw) {
  const float* src; short* dst; int K, N;
  switch (blockIdx.y) {
    case 0: src = w0; dst = wsw + OFF_FE_W0T; K = 320; N = 256; break;
    case 1: src = w1; dst = wsw + OFF_FE_W1T; K = 256; N = 256; break;
    case 2: src = w2; dst = wsw + OFF_FE_W2T; K = 256; N = 128; break;
    case 3: src = w3; dst = wsw + OFF_FN_W0T; K = 256; N = 256; break;
    case 4: src = w4; dst = wsw + OFF_FN_W1T; K = 256; N = 256; break;
    default: src = w5; dst = wsw + OFF_FN_W2T; K = 256; N = 128; break;
  }
  int idx = blockIdx.x * 256 + threadIdx.x;
  if (idx < K * N) {
    int k = idx / N;
    int n = idx - k * N;
    dst[n * K + k] = f2bf(src[idx]);
  }
}

__global__ void cvt_bf16(const float* __restrict__ src, short* __restrict__ dst, int n8) {
  int i = blockIdx.x * 256 + threadIdx.x;
  if (i < n8) {
    float4 v0 = ((const float4*)src)[i * 2];
    float4 v1 = ((const float4*)src)[i * 2 + 1];
    short8 pk;
    pk[0] = f2bf(v0.x); pk[1] = f2bf(v0.y); pk[2] = f2bf(v0.z); pk[3] = f2bf(v0.w);
    pk[4] = f2bf(v1.x); pk[5] = f2bf(v1.y); pk[6] = f2bf(v1.z); pk[7] = f2bf(v1.w);
    ((short8*)dst)[i] = pk;
  }
}

__global__ void hist_kernel(const int* __restrict__ receivers, int* __restrict__ cnt) {
  int e = blockIdx.x * 512 + threadIdx.x;
  if (e < NEDGES) atomicAdd(&cnt[receivers[e]], 1);
}

__global__ __launch_bounds__(1024) void scan1_kernel(const int* __restrict__ cnt,
                                                     int* __restrict__ base,
                                                     int* __restrict__ bsum) {
  __shared__ int s[1024];
  const int tid = threadIdx.x;
  int i = blockIdx.x * 1024 + tid;
  int v = (i < NNODES) ? cnt[i] : 0;
  s[tid] = v;
  __syncthreads();
  for (int off = 1; off < 1024; off <<= 1) {
    int t = (tid >= off) ? s[tid - off] : 0;
    __syncthreads();
    s[tid] += t;
    __syncthreads();
  }
  if (i < NNODES) base[i] = s[tid] - v;
  if (tid == 1023) bsum[blockIdx.x] = s[1023];
}

__global__ void scan2_kernel(int* __restrict__ bsum, int nblk) {
  if (threadIdx.x == 0) {
    int run = 0;
    for (int b = 0; b < nblk; ++b) { int t = bsum[b]; bsum[b] = run; run += t; }
  }
}

__global__ __launch_bounds__(1024) void scan3_kernel(const int* __restrict__ bsum,
                                                     int* __restrict__ base,
                                                     int* __restrict__ cursor) {
  int i = blockIdx.x * 1024 + threadIdx.x;
  if (i < NNODES) {
    int b = base[i] + bsum[blockIdx.x];
    base[i] = b;
    cursor[i] = b;
  }
  if (i == 0) base[NNODES] = NEDGES;
}

__global__ void scatter_kernel(const int* __restrict__ receivers, int* __restrict__ cursor,
                               int* __restrict__ eidx) {
  int e = blockIdx.x * 512 + threadIdx.x;
  if (e < NEDGES) {
    int pos = atomicAdd(&cursor[receivers[e]], 1);
    eidx[pos] = e;
  }
}

extern "C" void kernel_launch(void* const* d_in, const int* in_sizes, int n_in,
                              void* d_out, int out_size, void* d_ws, size_t ws_size,
                              hipStream_t stream) {
  const float* node_attrs = (const float*)d_in[0];
  const float* edge_attrs = (const float*)d_in[1];
  const int* senders = (const int*)d_in[2];
  const int* receivers = (const int*)d_in[3];
  const float* fe_W0 = (const float*)d_in[4];
  const float* fe_b0 = (const float*)d_in[5];
  const float* fe_W1 = (const float*)d_in[6];
  const float* fe_b1 = (const float*)d_in[7];
  const float* fe_W2 = (const float*)d_in[8];
  const float* fe_b2 = (const float*)d_in[9];
  const float* fn_W0 = (const float*)d_in[10];
  const float* fn_b0 = (const float*)d_in[11];
  const float* fn_W1 = (const float*)d_in[12];
  const float* fn_b1 = (const float*)d_in[13];
  const float* fn_W2 = (const float*)d_in[14];
  const float* fn_b2 = (const float*)d_in[15];

  short* wsw  = (short*)d_ws;
  int* cnt    = (int*)((char*)d_ws + OFF_CNT_B);
  int* basep  = (int*)((char*)d_ws + OFF_BASE_B);
  int* cursor = (int*)((char*)d_ws + OFF_CURSOR_B);
  int* eidx   = (int*)((char*)d_ws + OFF_EIDX_B);
  int* bsum   = (int*)((char*)d_ws + OFF_BSUM_B);
  short* nbf  = (short*)((char*)d_ws + OFF_NBF_B);
  short* Yt   = (short*)((char*)d_ws + OFF_Y_B);
  short* ecopy = (ws_size >= ECOPY_NEED) ? (short*)((char*)d_ws + OFF_ECOPY_B) : nullptr;
  float* out = (float*)d_out;
  float* n_out = out;                                  // [50000][128] first
  float* e_out = out + (size_t)NNODES * 128;           // then [800000][128]

  dim3 gprep(320, 6);
  prep_weights_all<<<gprep, 256, 0, stream>>>(fe_W0, fe_W1, fe_W2, fn_W0, fn_W1, fn_W2, wsw);
  cvt_bf16<<<(NNODES * 128 / 8 + 255) / 256, 256, 0, stream>>>(node_attrs, nbf, NNODES * 128 / 8);
  hipMemsetAsync(cnt, 0, NNODES * sizeof(int), stream);

  yprep_kernel<<<(NNODES + 63) / 64, 512, 0, stream>>>(nbf, wsw + OFF_FE_W0T, Yt);

  const int nscan = (NNODES + 1023) / 1024;   // 49
  hist_kernel<<<(NEDGES + 511) / 512, 512, 0, stream>>>(receivers, cnt);
  scan1_kernel<<<nscan, 1024, 0, stream>>>(cnt, basep, bsum);
  scan2_kernel<<<1, 64, 0, stream>>>(bsum, nscan);
  scan3_kernel<<<nscan, 1024, 0, stream>>>(bsum, basep, cursor);
  scatter_kernel<<<(NEDGES + 511) / 512, 512, 0, stream>>>(receivers, cursor, eidx);

  edge_kernel<<<NEDGES / 64, 512, 0, stream>>>(Yt, edge_attrs, senders, receivers,
                                               wsw, fe_b0, fe_b1, fe_b2, e_out, ecopy);
  node_kernel<<<(NNODES + 63) / 64, 512, 0, stream>>>(nbf, e_out, ecopy, basep, eidx, wsw,
                                                      fn_b0, fn_b1, fn_b2, n_out);
}